// Round 6
// baseline (159.645 us; speedup 1.0000x reference)
//
#include <hip/hip_runtime.h>
#include <hip/hip_fp16.h>
#include <math.h>

#define B_ 4
#define K_ 4
#define D_ 96
#define L_ 2048
#define N_ 16
#define R_ 6
#define C_ 38          // R + 2N
#define CH 16          // l's per thread in scan (measured optimum: 8->52us, 16->40us, 32->84us)
#define TPR 128        // threads per row = L_/CH

__device__ __forceinline__ float softplus_f(float x) {
    return fmaxf(x, 0.f) + __logf(1.f + __expf(-fabsf(x)));
}

#if __has_builtin(__builtin_amdgcn_exp2f)
__device__ __forceinline__ float exp2_fast(float x) { return __builtin_amdgcn_exp2f(x); }
#else
__device__ __forceinline__ float exp2_fast(float x) { return __expf(0.6931471805599453f * x); }
#endif

__device__ __forceinline__ float h2f(const uint4& v, int e) {
    return __half2float(((const __half*)&v)[e]);
}

// BC layout (fp16, chunk-interleaved for CH=16 wave-coalesced scan reads):
//   uint4 (=8 halfs) at index (((bk*16 + i)*4 + j)*128 + t), where l = t*16+i
//   j=0: B n0..7   j=1: B n8..15   j=2: C n0..7   j=3: C n8..15

// ---------------------------------------------------------------------------
// Proj v3 (keep): 4-way d-split for occupancy. Block 256 = 4 d-groups x 64
// l's; LDS-combine; dg==0 stores. grid (B*K, 32, 2) = 1024 blocks.
// ---------------------------------------------------------------------------
__global__ __launch_bounds__(256) void proj_kernel(
    const float* __restrict__ xs, const float* __restrict__ xpw,
    uint4* __restrict__ BCc, float* __restrict__ dts_ws)
{
    __shared__ float sWt[D_][24];
    __shared__ float sRed[3][64][25];   // partials from dg=1..3; stride 25 = conflict-free
    const int bk = blockIdx.x;
    const int k = bk & 3;
    const int cg = blockIdx.z;
    const int tid = threadIdx.x;
    const int dg = tid >> 6;            // d-group 0..3 (24 d's each)
    const int li = tid & 63;            // l within block

    for (int idx = tid; idx < 24 * D_; idx += 256) {
        const int m = idx / D_, dd = idx % D_;   // coalesced over dd
        float wv = 0.f;
        if (cg == 0) {
            if (m < 16)      wv = xpw[(k * C_ + R_ + m) * D_ + dd];        // B rows
            else if (m < 22) wv = xpw[(k * C_ + (m - 16)) * D_ + dd];      // dt rows
        } else {
            if (m < 16)      wv = xpw[(k * C_ + R_ + 16 + m) * D_ + dd];   // C rows
        }
        sWt[dd][m] = wv;
    }
    __syncthreads();

    const int l = blockIdx.y * 64 + li;
    const float* Xl = xs + (size_t)bk * D_ * L_ + l;

    float acc[24];
#pragma unroll
    for (int m = 0; m < 24; ++m) acc[m] = 0.f;

#pragma unroll
    for (int dd = 0; dd < 24; ++dd) {
        const int d = dg * 24 + dd;
        const float xv = Xl[(size_t)d * L_];
#pragma unroll
        for (int q = 0; q < 6; ++q) {
            const float4 w = *(const float4*)&sWt[d][q * 4];  // broadcast within dg
            acc[q * 4 + 0] = fmaf(w.x, xv, acc[q * 4 + 0]);
            acc[q * 4 + 1] = fmaf(w.y, xv, acc[q * 4 + 1]);
            acc[q * 4 + 2] = fmaf(w.z, xv, acc[q * 4 + 2]);
            acc[q * 4 + 3] = fmaf(w.w, xv, acc[q * 4 + 3]);
        }
    }

    if (dg > 0) {
#pragma unroll
        for (int m = 0; m < 24; ++m) sRed[dg - 1][li][m] = acc[m];
    }
    __syncthreads();
    if (dg == 0) {
#pragma unroll
        for (int m = 0; m < 24; ++m)
            acc[m] += sRed[0][li][m] + sRed[1][li][m] + sRed[2][li][m];

        const int i8 = l & 15, t8 = l >> 4;
        const int jb = cg * 2;                 // cg0 -> j=0,1 (B); cg1 -> j=2,3 (C)
        union { __half h[8]; uint4 v; } p0, p1;
#pragma unroll
        for (int e = 0; e < 8; ++e) {
            p0.h[e] = __float2half(acc[e]);
            p1.h[e] = __float2half(acc[8 + e]);
        }
        BCc[(((size_t)bk * 16 + i8) * 4 + jb) * TPR + t8] = p0.v;
        BCc[(((size_t)bk * 16 + i8) * 4 + jb + 1) * TPR + t8] = p1.v;

        if (cg == 0) {
#pragma unroll
            for (int r = 0; r < R_; ++r)
                dts_ws[((size_t)bk * R_ + r) * L_ + l] = acc[16 + r];
        }
    }
}

// ---------------------------------------------------------------------------
// Scan v7: v6 body verbatim, but grid 768 blocks x 2 sequential bkd's per
// block (bkd = 2*bid + rep). 768 blocks = 3 blocks/CU = 12 waves/CU fits in
// ONE residency round even at the 4-waves/SIMD VGPR tier (1536 blocks was
// 1.5 rounds, second round half-empty). The two reps share bk -> BC/dts
// tiles stay L2-warm. Tests the residency theory with no tier gamble.
// Rolled rep loop (no unroll) to keep register pressure at v6 levels.
// ---------------------------------------------------------------------------
__global__ __launch_bounds__(256) void scan_kernel(
    const float* __restrict__ xs, const float* __restrict__ A_logs,
    const float* __restrict__ Ds, const float* __restrict__ dtw,
    const float* __restrict__ dtb, const float* __restrict__ dts_ws,
    const uint4* __restrict__ BCc, float* __restrict__ out)
{
    __shared__ float sAw[4][8];
    __shared__ float sBw[4][8];
    __shared__ float sy[TPR][17];   // stride 17: worst 2-way conflict = free

    const int tid = threadIdx.x;
    const int g = tid >> 7;          // n-half 0/1
    const int t = tid & (TPR - 1);   // l-chunk owner
    const int lane = tid & 63;
    const int gw = tid >> 6;         // wave 0..3; group g owns waves 2g, 2g+1

#pragma unroll 1
    for (int rep = 0; rep < 2; ++rep) {
        const int bkd = blockIdx.x * 2 + rep;
        const int d = bkd % D_;
        const int bk = bkd / D_;
        const int k = bk & 3;
        const int kd = k * D_ + d;

        const uint4* BC = BCc + (size_t)bk * 16 * 4 * TPR;
        const int jB = g, jC = 2 + g;

        // xs chunk -> registers (4x float4); doubles as y buffer in phase 3
        const float4* xv4 = (const float4*)(xs + (size_t)bkd * L_);
        float x[CH];
#pragma unroll
        for (int q = 0; q < 4; ++q)
            *(float4*)&x[q * 4] = xv4[t * 4 + q];

        // delta chunk
        float del[CH];
        const float bias = dtb[kd];
#pragma unroll
        for (int j = 0; j < CH; ++j) del[j] = bias;
        const float* w2 = dtw + (size_t)kd * R_;
        const float4* dts4 = (const float4*)(dts_ws + (size_t)bk * R_ * L_);
#pragma unroll
        for (int r = 0; r < R_; ++r) {
            const float wr = w2[r];
#pragma unroll
            for (int q = 0; q < 4; ++q) {
                const float4 tv = dts4[r * (L_ / 4) + t * 4 + q];
                del[q * 4 + 0] = fmaf(wr, tv.x, del[q * 4 + 0]);
                del[q * 4 + 1] = fmaf(wr, tv.y, del[q * 4 + 1]);
                del[q * 4 + 2] = fmaf(wr, tv.z, del[q * 4 + 2]);
                del[q * 4 + 3] = fmaf(wr, tv.w, del[q * 4 + 3]);
            }
        }
        float S = 0.f;
#pragma unroll
        for (int j = 0; j < CH; ++j) { del[j] = softplus_f(del[j]); S += del[j]; }

        float A2[8];
        const float* Ap = A_logs + (size_t)kd * N_ + g * 8;
#pragma unroll
        for (int n = 0; n < 8; ++n) A2[n] = -__expf(Ap[n]) * 1.44269504f;
        const float Dval = Ds[kd];

        // Phase 1: per-chunk b-aggregate over this n-half (a via exp2-of-sum)
        float a[8], b[8];
#pragma unroll
        for (int n = 0; n < 8; ++n) b[n] = 0.f;
#pragma unroll
        for (int i = 0; i < CH; ++i) {
            const uint4 cB = BC[(i * 4 + jB) * TPR + t];
            const float dl = del[i];
            const float dx = dl * x[i];
#pragma unroll
            for (int n = 0; n < 8; ++n) {
                const float dA = exp2_fast(dl * A2[n]);
                b[n] = fmaf(dA, b[n], dx * h2f(cB, n));
            }
        }
#pragma unroll
        for (int n = 0; n < 8; ++n) a[n] = exp2_fast(S * A2[n]);

        // Phase 2a: wave-level inclusive scan (8 n's)
#pragma unroll
        for (int off = 1; off < 64; off <<= 1) {
#pragma unroll
            for (int n = 0; n < 8; ++n) {
                const float pa = __shfl_up(a[n], off, 64);
                const float pb = __shfl_up(b[n], off, 64);
                if (lane >= off) {
                    b[n] = fmaf(a[n], pb, b[n]);
                    a[n] *= pa;
                }
            }
        }
        // Phase 2b: cross-wave fixup (2 waves per group)
        if (lane == 63) {
#pragma unroll
            for (int n = 0; n < 8; ++n) { sAw[gw][n] = a[n]; sBw[gw][n] = b[n]; }
        }
        __syncthreads();

        // h0 = state entering this thread's chunk
        float h[8];
#pragma unroll
        for (int n = 0; n < 8; ++n) {
            float ae = __shfl_up(a[n], 1, 64);
            float be = __shfl_up(b[n], 1, 64);
            if (lane == 0) { ae = 1.f; be = 0.f; }
            float wb = 0.f;
            for (int w = g * 2; w < gw; ++w) wb = fmaf(sAw[w][n], wb, sBw[w][n]);
            h[n] = fmaf(ae, wb, be);
        }

        // Phase 3: re-run chunk with true initial state; y written over x[]
#pragma unroll
        for (int i = 0; i < CH; ++i) {
            const uint4 cB = BC[(i * 4 + jB) * TPR + t];
            const uint4 cC = BC[(i * 4 + jC) * TPR + t];
            const float dl = del[i];
            const float xi = x[i];
            const float dx = dl * xi;
            float y = (g == 0) ? Dval * xi : 0.f;
#pragma unroll
            for (int n = 0; n < 8; ++n) {
                const float dA = exp2_fast(dl * A2[n]);
                h[n] = fmaf(dA, h[n], dx * h2f(cB, n));
                y = fmaf(h[n], h2f(cC, n), y);
            }
            x[i] = y;
        }

        // Combine group partials and store
        if (g == 1) {
#pragma unroll
            for (int j = 0; j < CH; ++j) sy[t][j] = x[j];
        }
        __syncthreads();
        if (g == 0) {
#pragma unroll
            for (int j = 0; j < CH; ++j) x[j] += sy[t][j];
            float4* ov = (float4*)(out + (size_t)bkd * L_);
#pragma unroll
            for (int q = 0; q < 4; ++q)
                ov[t * 4 + q] = make_float4(x[q * 4], x[q * 4 + 1],
                                            x[q * 4 + 2], x[q * 4 + 3]);
        }
        __syncthreads();   // protect sAw/sBw/sy reuse across reps
    }
}

extern "C" void kernel_launch(void* const* d_in, const int* in_sizes, int n_in,
                              void* d_out, int out_size, void* d_ws, size_t ws_size,
                              hipStream_t stream) {
    const float* xs = (const float*)d_in[0];       // (B,K,D,L)
    const float* A_logs = (const float*)d_in[1];   // (K*D, N)
    const float* Ds = (const float*)d_in[2];       // (K*D,)
    const float* dtw = (const float*)d_in[3];      // (K,D,R)
    const float* dtb = (const float*)d_in[4];      // (K,D)
    const float* xpw = (const float*)d_in[5];      // (K,C,D)
    float* out = (float*)d_out;                    // (B,K,D,L) fp32

    uint4* BCc = (uint4*)d_ws;                     // 16*16*4*128 uint4 = 2 MB
    float* dts_ws = (float*)(BCc + (size_t)B_ * K_ * 16 * 4 * TPR);  // 768 KB

    proj_kernel<<<dim3(B_ * K_, 32, 2), 256, 0, stream>>>(xs, xpw, BCc, dts_ws);
    scan_kernel<<<(B_ * K_ * D_) / 2, 256, 0, stream>>>(
        xs, A_logs, Ds, dtw, dtb, dts_ws, BCc, out);
}

// Round 7
// 113.179 us; speedup vs baseline: 1.4106x; 1.4106x over previous
//
#include <hip/hip_runtime.h>
#include <hip/hip_fp16.h>
#include <math.h>

#define B_ 4
#define K_ 4
#define D_ 96
#define L_ 2048
#define N_ 16
#define R_ 6
#define C_ 38          // R + 2N
#define CH 16          // l's per thread in scan
#define TPR 128        // threads per row = L_/CH

__device__ __forceinline__ float softplus_f(float x) {
    return fmaxf(x, 0.f) + __logf(1.f + __expf(-fabsf(x)));
}

#if __has_builtin(__builtin_amdgcn_exp2f)
__device__ __forceinline__ float exp2_fast(float x) { return __builtin_amdgcn_exp2f(x); }
#else
__device__ __forceinline__ float exp2_fast(float x) { return __expf(0.6931471805599453f * x); }
#endif

__device__ __forceinline__ float h2f(const uint4& v, int e) {
    return __half2float(((const __half*)&v)[e]);
}

// BC layout (fp16, chunk-interleaved for CH=16 wave-coalesced scan reads):
//   uint4 (=8 halfs) at index (((bk*16 + i)*4 + j)*128 + t), where l = t*16+i
//   j=0: B n0..7   j=1: B n8..15   j=2: C n0..7   j=3: C n8..15

// ---------------------------------------------------------------------------
// Proj v3 (keep): 4-way d-split for occupancy. Block 256 = 4 d-groups x 64
// l's; LDS-combine; dg==0 stores. grid (B*K, 32, 2) = 1024 blocks.
// ---------------------------------------------------------------------------
__global__ __launch_bounds__(256) void proj_kernel(
    const float* __restrict__ xs, const float* __restrict__ xpw,
    uint4* __restrict__ BCc, float* __restrict__ dts_ws)
{
    __shared__ float sWt[D_][24];
    __shared__ float sRed[3][64][25];   // partials from dg=1..3; stride 25 = conflict-free
    const int bk = blockIdx.x;
    const int k = bk & 3;
    const int cg = blockIdx.z;
    const int tid = threadIdx.x;
    const int dg = tid >> 6;            // d-group 0..3 (24 d's each)
    const int li = tid & 63;            // l within block

    for (int idx = tid; idx < 24 * D_; idx += 256) {
        const int m = idx / D_, dd = idx % D_;   // coalesced over dd
        float wv = 0.f;
        if (cg == 0) {
            if (m < 16)      wv = xpw[(k * C_ + R_ + m) * D_ + dd];        // B rows
            else if (m < 22) wv = xpw[(k * C_ + (m - 16)) * D_ + dd];      // dt rows
        } else {
            if (m < 16)      wv = xpw[(k * C_ + R_ + 16 + m) * D_ + dd];   // C rows
        }
        sWt[dd][m] = wv;
    }
    __syncthreads();

    const int l = blockIdx.y * 64 + li;
    const float* Xl = xs + (size_t)bk * D_ * L_ + l;

    float acc[24];
#pragma unroll
    for (int m = 0; m < 24; ++m) acc[m] = 0.f;

#pragma unroll
    for (int dd = 0; dd < 24; ++dd) {
        const int d = dg * 24 + dd;
        const float xv = Xl[(size_t)d * L_];
#pragma unroll
        for (int q = 0; q < 6; ++q) {
            const float4 w = *(const float4*)&sWt[d][q * 4];  // broadcast within dg
            acc[q * 4 + 0] = fmaf(w.x, xv, acc[q * 4 + 0]);
            acc[q * 4 + 1] = fmaf(w.y, xv, acc[q * 4 + 1]);
            acc[q * 4 + 2] = fmaf(w.z, xv, acc[q * 4 + 2]);
            acc[q * 4 + 3] = fmaf(w.w, xv, acc[q * 4 + 3]);
        }
    }

    if (dg > 0) {
#pragma unroll
        for (int m = 0; m < 24; ++m) sRed[dg - 1][li][m] = acc[m];
    }
    __syncthreads();
    if (dg == 0) {
#pragma unroll
        for (int m = 0; m < 24; ++m)
            acc[m] += sRed[0][li][m] + sRed[1][li][m] + sRed[2][li][m];

        const int i8 = l & 15, t8 = l >> 4;
        const int jb = cg * 2;                 // cg0 -> j=0,1 (B); cg1 -> j=2,3 (C)
        union { __half h[8]; uint4 v; } p0, p1;
#pragma unroll
        for (int e = 0; e < 8; ++e) {
            p0.h[e] = __float2half(acc[e]);
            p1.h[e] = __float2half(acc[8 + e]);
        }
        BCc[(((size_t)bk * 16 + i8) * 4 + jb) * TPR + t8] = p0.v;
        BCc[(((size_t)bk * 16 + i8) * 4 + jb + 1) * TPR + t8] = p1.v;

        if (cg == 0) {
#pragma unroll
            for (int r = 0; r < R_; ++r)
                dts_ws[((size_t)bk * R_ + r) * L_ + l] = acc[16 + r];
        }
    }
}

// ---------------------------------------------------------------------------
// Scan v8: back to 1536 blocks (round-6 proved fewer/bigger blocks lose 2x).
// Attack the diagnosed bottleneck (140 VGPR -> 3 waves/SIMD, 77% stall):
//   - x[16]/del[16] moved to LDS (stride-17: 2-way conflict = free); read
//     back per-iteration in phases 1/3. Removes 32 long-lived VGPRs.
//   - del computed ONCE (g=0 only) instead of per n-group; S via LDS.
//   - g=1 writes y per-i to sy; g=0 keeps yv only during phase 3 (a/b dead).
// Natural allocation, no launch-bounds cap (round-3 lesson). Target VGPR
// ~85-110 -> 4-5 waves/SIMD instead of 3.
// ---------------------------------------------------------------------------
__global__ __launch_bounds__(256) void scan_kernel(
    const float* __restrict__ xs, const float* __restrict__ A_logs,
    const float* __restrict__ Ds, const float* __restrict__ dtw,
    const float* __restrict__ dtb, const float* __restrict__ dts_ws,
    const uint4* __restrict__ BCc, float* __restrict__ out)
{
    __shared__ float sAw[4][8];
    __shared__ float sBw[4][8];
    __shared__ float sx[TPR][17];    // x chunk, shared by both n-groups
    __shared__ float sdel[TPR][17];  // del chunk, shared by both n-groups
    __shared__ float sy[TPR][17];    // g=1 partial y
    __shared__ float sS[TPR];        // sum(del) per chunk

    const int bkd = blockIdx.x;
    const int d = bkd % D_;
    const int bk = bkd / D_;
    const int k = bk & 3;
    const int kd = k * D_ + d;
    const int tid = threadIdx.x;
    const int g = tid >> 7;          // n-half 0/1
    const int t = tid & (TPR - 1);   // l-chunk owner
    const int lane = tid & 63;
    const int gw = tid >> 6;         // wave 0..3; group g owns waves 2g, 2g+1

    const uint4* BC = BCc + (size_t)bk * 16 * 4 * TPR;
    const int jB = g, jC = 2 + g;

    // Per-thread constants (both groups; cheap, before the staging barrier)
    float A2[8];
    const float* Ap = A_logs + (size_t)kd * N_ + g * 8;
#pragma unroll
    for (int n = 0; n < 8; ++n) A2[n] = -__expf(Ap[n]) * 1.44269504f;
    const float Dval = Ds[kd];

    // Staging (g=0 waves only): del once, x once -> LDS
    if (g == 0) {
        float del[CH];
        const float bias = dtb[kd];
#pragma unroll
        for (int j = 0; j < CH; ++j) del[j] = bias;
        const float* w2 = dtw + (size_t)kd * R_;
        const float4* dts4 = (const float4*)(dts_ws + (size_t)bk * R_ * L_);
#pragma unroll
        for (int r = 0; r < R_; ++r) {
            const float wr = w2[r];
#pragma unroll
            for (int q = 0; q < 4; ++q) {
                const float4 tv = dts4[r * (L_ / 4) + t * 4 + q];
                del[q * 4 + 0] = fmaf(wr, tv.x, del[q * 4 + 0]);
                del[q * 4 + 1] = fmaf(wr, tv.y, del[q * 4 + 1]);
                del[q * 4 + 2] = fmaf(wr, tv.z, del[q * 4 + 2]);
                del[q * 4 + 3] = fmaf(wr, tv.w, del[q * 4 + 3]);
            }
        }
        float S = 0.f;
#pragma unroll
        for (int j = 0; j < CH; ++j) {
            del[j] = softplus_f(del[j]);
            S += del[j];
            sdel[t][j] = del[j];
        }
        sS[t] = S;

        const float4* xv4 = (const float4*)(xs + (size_t)bkd * L_);
#pragma unroll
        for (int q = 0; q < 4; ++q) {
            const float4 xv = xv4[t * 4 + q];
            sx[t][q * 4 + 0] = xv.x;
            sx[t][q * 4 + 1] = xv.y;
            sx[t][q * 4 + 2] = xv.z;
            sx[t][q * 4 + 3] = xv.w;
        }
    }
    __syncthreads();

    const float S = sS[t];

    // Phase 1: per-chunk b-aggregate over this n-half (a via exp2-of-sum)
    float a[8], b[8];
#pragma unroll
    for (int n = 0; n < 8; ++n) b[n] = 0.f;
#pragma unroll
    for (int i = 0; i < CH; ++i) {
        const uint4 cB = BC[(i * 4 + jB) * TPR + t];
        const float dl = sdel[t][i];
        const float dx = dl * sx[t][i];
#pragma unroll
        for (int n = 0; n < 8; ++n) {
            const float dA = exp2_fast(dl * A2[n]);
            b[n] = fmaf(dA, b[n], dx * h2f(cB, n));
        }
    }
#pragma unroll
    for (int n = 0; n < 8; ++n) a[n] = exp2_fast(S * A2[n]);

    // Phase 2a: wave-level inclusive scan (8 n's)
#pragma unroll
    for (int off = 1; off < 64; off <<= 1) {
#pragma unroll
        for (int n = 0; n < 8; ++n) {
            const float pa = __shfl_up(a[n], off, 64);
            const float pb = __shfl_up(b[n], off, 64);
            if (lane >= off) {
                b[n] = fmaf(a[n], pb, b[n]);
                a[n] *= pa;
            }
        }
    }
    // Phase 2b: cross-wave fixup (2 waves per group)
    if (lane == 63) {
#pragma unroll
        for (int n = 0; n < 8; ++n) { sAw[gw][n] = a[n]; sBw[gw][n] = b[n]; }
    }
    __syncthreads();

    // h0 = state entering this thread's chunk
    float h[8];
#pragma unroll
    for (int n = 0; n < 8; ++n) {
        float ae = __shfl_up(a[n], 1, 64);
        float be = __shfl_up(b[n], 1, 64);
        if (lane == 0) { ae = 1.f; be = 0.f; }
        float wb = 0.f;
        for (int w = g * 2; w < gw; ++w) wb = fmaf(sAw[w][n], wb, sBw[w][n]);
        h[n] = fmaf(ae, wb, be);
    }

    // Phase 3: re-run chunk with true initial state
    float yv[CH];   // live only here, and only meaningfully for g=0
#pragma unroll
    for (int i = 0; i < CH; ++i) {
        const uint4 cB = BC[(i * 4 + jB) * TPR + t];
        const uint4 cC = BC[(i * 4 + jC) * TPR + t];
        const float dl = sdel[t][i];
        const float xi = sx[t][i];
        const float dx = dl * xi;
        float y = (g == 0) ? Dval * xi : 0.f;
#pragma unroll
        for (int n = 0; n < 8; ++n) {
            const float dA = exp2_fast(dl * A2[n]);
            h[n] = fmaf(dA, h[n], dx * h2f(cB, n));
            y = fmaf(h[n], h2f(cC, n), y);
        }
        if (g == 1) sy[t][i] = y; else yv[i] = y;
    }
    __syncthreads();

    // Combine group partials and store
    if (g == 0) {
#pragma unroll
        for (int j = 0; j < CH; ++j) yv[j] += sy[t][j];
        float4* ov = (float4*)(out + (size_t)bkd * L_);
#pragma unroll
        for (int q = 0; q < 4; ++q)
            ov[t * 4 + q] = make_float4(yv[q * 4], yv[q * 4 + 1],
                                        yv[q * 4 + 2], yv[q * 4 + 3]);
    }
}

extern "C" void kernel_launch(void* const* d_in, const int* in_sizes, int n_in,
                              void* d_out, int out_size, void* d_ws, size_t ws_size,
                              hipStream_t stream) {
    const float* xs = (const float*)d_in[0];       // (B,K,D,L)
    const float* A_logs = (const float*)d_in[1];   // (K*D, N)
    const float* Ds = (const float*)d_in[2];       // (K*D,)
    const float* dtw = (const float*)d_in[3];      // (K,D,R)
    const float* dtb = (const float*)d_in[4];      // (K,D)
    const float* xpw = (const float*)d_in[5];      // (K,C,D)
    float* out = (float*)d_out;                    // (B,K,D,L) fp32

    uint4* BCc = (uint4*)d_ws;                     // 16*16*4*128 uint4 = 2 MB
    float* dts_ws = (float*)(BCc + (size_t)B_ * K_ * 16 * 4 * TPR);  // 768 KB

    proj_kernel<<<dim3(B_ * K_, 32, 2), 256, 0, stream>>>(xs, xpw, BCc, dts_ws);
    scan_kernel<<<B_ * K_ * D_, 256, 0, stream>>>(
        xs, A_logs, Ds, dtw, dtb, dts_ws, BCc, out);
}

// Round 8
// 110.687 us; speedup vs baseline: 1.4423x; 1.0225x over previous
//
#include <hip/hip_runtime.h>
#include <hip/hip_fp16.h>
#include <math.h>

#define B_ 4
#define K_ 4
#define D_ 96
#define L_ 2048
#define N_ 16
#define R_ 6
#define C_ 38          // R + 2N
#define CH 16          // l's per thread in scan
#define TPR 128        // threads per row = L_/CH

__device__ __forceinline__ float softplus_f(float x) {
    return fmaxf(x, 0.f) + __logf(1.f + __expf(-fabsf(x)));
}

#if __has_builtin(__builtin_amdgcn_exp2f)
__device__ __forceinline__ float exp2_fast(float x) { return __builtin_amdgcn_exp2f(x); }
#else
__device__ __forceinline__ float exp2_fast(float x) { return __expf(0.6931471805599453f * x); }
#endif

__device__ __forceinline__ float h2f(const uint4& v, int e) {
    return __half2float(((const __half*)&v)[e]);
}

// BC layout (fp16, chunk-interleaved for CH=16 wave-coalesced scan reads):
//   uint4 (=8 halfs) at index (((bk*16 + i)*4 + j)*128 + t), where l = t*16+i
//   j=0: B n0..7   j=1: B n8..15   j=2: C n0..7   j=3: C n8..15

// ---------------------------------------------------------------------------
// Proj v3 (keep): 4-way d-split for occupancy. Block 256 = 4 d-groups x 64
// l's; LDS-combine; dg==0 stores. grid (B*K, 32, 2) = 1024 blocks.
// ---------------------------------------------------------------------------
__global__ __launch_bounds__(256) void proj_kernel(
    const float* __restrict__ xs, const float* __restrict__ xpw,
    uint4* __restrict__ BCc, float* __restrict__ dts_ws)
{
    __shared__ float sWt[D_][24];
    __shared__ float sRed[3][64][25];   // partials from dg=1..3; stride 25 = conflict-free
    const int bk = blockIdx.x;
    const int k = bk & 3;
    const int cg = blockIdx.z;
    const int tid = threadIdx.x;
    const int dg = tid >> 6;            // d-group 0..3 (24 d's each)
    const int li = tid & 63;            // l within block

    for (int idx = tid; idx < 24 * D_; idx += 256) {
        const int m = idx / D_, dd = idx % D_;   // coalesced over dd
        float wv = 0.f;
        if (cg == 0) {
            if (m < 16)      wv = xpw[(k * C_ + R_ + m) * D_ + dd];        // B rows
            else if (m < 22) wv = xpw[(k * C_ + (m - 16)) * D_ + dd];      // dt rows
        } else {
            if (m < 16)      wv = xpw[(k * C_ + R_ + 16 + m) * D_ + dd];   // C rows
        }
        sWt[dd][m] = wv;
    }
    __syncthreads();

    const int l = blockIdx.y * 64 + li;
    const float* Xl = xs + (size_t)bk * D_ * L_ + l;

    float acc[24];
#pragma unroll
    for (int m = 0; m < 24; ++m) acc[m] = 0.f;

#pragma unroll
    for (int dd = 0; dd < 24; ++dd) {
        const int d = dg * 24 + dd;
        const float xv = Xl[(size_t)d * L_];
#pragma unroll
        for (int q = 0; q < 6; ++q) {
            const float4 w = *(const float4*)&sWt[d][q * 4];  // broadcast within dg
            acc[q * 4 + 0] = fmaf(w.x, xv, acc[q * 4 + 0]);
            acc[q * 4 + 1] = fmaf(w.y, xv, acc[q * 4 + 1]);
            acc[q * 4 + 2] = fmaf(w.z, xv, acc[q * 4 + 2]);
            acc[q * 4 + 3] = fmaf(w.w, xv, acc[q * 4 + 3]);
        }
    }

    if (dg > 0) {
#pragma unroll
        for (int m = 0; m < 24; ++m) sRed[dg - 1][li][m] = acc[m];
    }
    __syncthreads();
    if (dg == 0) {
#pragma unroll
        for (int m = 0; m < 24; ++m)
            acc[m] += sRed[0][li][m] + sRed[1][li][m] + sRed[2][li][m];

        const int i8 = l & 15, t8 = l >> 4;
        const int jb = cg * 2;                 // cg0 -> j=0,1 (B); cg1 -> j=2,3 (C)
        union { __half h[8]; uint4 v; } p0, p1;
#pragma unroll
        for (int e = 0; e < 8; ++e) {
            p0.h[e] = __float2half(acc[e]);
            p1.h[e] = __float2half(acc[8 + e]);
        }
        BCc[(((size_t)bk * 16 + i8) * 4 + jb) * TPR + t8] = p0.v;
        BCc[(((size_t)bk * 16 + i8) * 4 + jb + 1) * TPR + t8] = p1.v;

        if (cg == 0) {
#pragma unroll
            for (int r = 0; r < R_; ++r)
                dts_ws[((size_t)bk * R_ + r) * L_ + l] = acc[16 + r];
        }
    }
}

// ---------------------------------------------------------------------------
// Scan v9: v8 structure with the two suspected neutralizers fixed:
//   1. BALANCED staging: all 256 threads compute del (half-chunk each: 8 l's)
//      and load x (2 float4 each) -> no idle g=1 waves during staging; del
//      still computed exactly once. S accumulated inside phase 1 (sS gone).
//   2. #pragma unroll 4 on phase-1/phase-3 i-loops: cap the compiler's ILP
//      window so the allocator lands at <=102 VGPR (5 waves/SIMD) NATURALLY
//      (round-3 lesson: never cap via launch_bounds).
// Arithmetic instruction-identical to v8 -> absmax unchanged.
// ---------------------------------------------------------------------------
__global__ __launch_bounds__(256) void scan_kernel(
    const float* __restrict__ xs, const float* __restrict__ A_logs,
    const float* __restrict__ Ds, const float* __restrict__ dtw,
    const float* __restrict__ dtb, const float* __restrict__ dts_ws,
    const uint4* __restrict__ BCc, float* __restrict__ out)
{
    __shared__ float sAw[4][8];
    __shared__ float sBw[4][8];
    __shared__ float sx[TPR][17];    // x chunk, shared by both n-groups
    __shared__ float sdel[TPR][17];  // del chunk, shared by both n-groups
    __shared__ float sy[TPR][17];    // g=1 partial y

    const int bkd = blockIdx.x;
    const int d = bkd % D_;
    const int bk = bkd / D_;
    const int k = bk & 3;
    const int kd = k * D_ + d;
    const int tid = threadIdx.x;
    const int g = tid >> 7;          // n-half 0/1
    const int t = tid & (TPR - 1);   // l-chunk owner
    const int lane = tid & 63;
    const int gw = tid >> 6;         // wave 0..3; group g owns waves 2g, 2g+1

    const uint4* BC = BCc + (size_t)bk * 16 * 4 * TPR;
    const int jB = g, jC = 2 + g;

    // Per-thread constants
    float A2[8];
    const float* Ap = A_logs + (size_t)kd * N_ + g * 8;
#pragma unroll
    for (int n = 0; n < 8; ++n) A2[n] = -__expf(Ap[n]) * 1.44269504f;
    const float Dval = Ds[kd];

    // Balanced staging: every thread handles HALF a chunk (8 l's) of del,
    // and 8 l's of x. tc = chunk, hc = half.
    {
        const int tc = tid >> 1;
        const int hc = tid & 1;
        float dl8[8];
        const float bias = dtb[kd];
#pragma unroll
        for (int j = 0; j < 8; ++j) dl8[j] = bias;
        const float* w2 = dtw + (size_t)kd * R_;
        const float4* dts4 = (const float4*)(dts_ws + (size_t)bk * R_ * L_);
#pragma unroll
        for (int r = 0; r < R_; ++r) {
            const float wr = w2[r];
#pragma unroll
            for (int q = 0; q < 2; ++q) {
                const float4 tv = dts4[r * (L_ / 4) + tid * 2 + q];
                dl8[q * 4 + 0] = fmaf(wr, tv.x, dl8[q * 4 + 0]);
                dl8[q * 4 + 1] = fmaf(wr, tv.y, dl8[q * 4 + 1]);
                dl8[q * 4 + 2] = fmaf(wr, tv.z, dl8[q * 4 + 2]);
                dl8[q * 4 + 3] = fmaf(wr, tv.w, dl8[q * 4 + 3]);
            }
        }
#pragma unroll
        for (int j = 0; j < 8; ++j) sdel[tc][hc * 8 + j] = softplus_f(dl8[j]);

        const float4* xv4 = (const float4*)(xs + (size_t)bkd * L_);
#pragma unroll
        for (int q = 0; q < 2; ++q) {
            const float4 xv = xv4[tid * 2 + q];
            const int l0 = tid * 8 + q * 4;
            const int row = l0 >> 4, col = l0 & 15;
            sx[row][col + 0] = xv.x;
            sx[row][col + 1] = xv.y;
            sx[row][col + 2] = xv.z;
            sx[row][col + 3] = xv.w;
        }
    }
    __syncthreads();

    // Phase 1: per-chunk b-aggregate over this n-half; S accumulated inline
    float b[8];
#pragma unroll
    for (int n = 0; n < 8; ++n) b[n] = 0.f;
    float S = 0.f;
#pragma unroll 4
    for (int i = 0; i < CH; ++i) {
        const uint4 cB = BC[(i * 4 + jB) * TPR + t];
        const float dl = sdel[t][i];
        S += dl;
        const float dx = dl * sx[t][i];
#pragma unroll
        for (int n = 0; n < 8; ++n) {
            const float dA = exp2_fast(dl * A2[n]);
            b[n] = fmaf(dA, b[n], dx * h2f(cB, n));
        }
    }
    float a[8];
#pragma unroll
    for (int n = 0; n < 8; ++n) a[n] = exp2_fast(S * A2[n]);

    // Phase 2a: wave-level inclusive scan (8 n's)
#pragma unroll
    for (int off = 1; off < 64; off <<= 1) {
#pragma unroll
        for (int n = 0; n < 8; ++n) {
            const float pa = __shfl_up(a[n], off, 64);
            const float pb = __shfl_up(b[n], off, 64);
            if (lane >= off) {
                b[n] = fmaf(a[n], pb, b[n]);
                a[n] *= pa;
            }
        }
    }
    // Phase 2b: cross-wave fixup (2 waves per group)
    if (lane == 63) {
#pragma unroll
        for (int n = 0; n < 8; ++n) { sAw[gw][n] = a[n]; sBw[gw][n] = b[n]; }
    }
    __syncthreads();

    // h0 = state entering this thread's chunk
    float h[8];
#pragma unroll
    for (int n = 0; n < 8; ++n) {
        float ae = __shfl_up(a[n], 1, 64);
        float be = __shfl_up(b[n], 1, 64);
        if (lane == 0) { ae = 1.f; be = 0.f; }
        float wb = 0.f;
        for (int w = g * 2; w < gw; ++w) wb = fmaf(sAw[w][n], wb, sBw[w][n]);
        h[n] = fmaf(ae, wb, be);
    }

    // Phase 3: re-run chunk with true initial state
    float yv[CH];   // live only here; meaningful for g=0
#pragma unroll 4
    for (int i = 0; i < CH; ++i) {
        const uint4 cB = BC[(i * 4 + jB) * TPR + t];
        const uint4 cC = BC[(i * 4 + jC) * TPR + t];
        const float dl = sdel[t][i];
        const float xi = sx[t][i];
        const float dx = dl * xi;
        float y = (g == 0) ? Dval * xi : 0.f;
#pragma unroll
        for (int n = 0; n < 8; ++n) {
            const float dA = exp2_fast(dl * A2[n]);
            h[n] = fmaf(dA, h[n], dx * h2f(cB, n));
            y = fmaf(h[n], h2f(cC, n), y);
        }
        if (g == 1) sy[t][i] = y; else yv[i] = y;
    }
    __syncthreads();

    // Combine group partials and store
    if (g == 0) {
#pragma unroll
        for (int j = 0; j < CH; ++j) yv[j] += sy[t][j];
        float4* ov = (float4*)(out + (size_t)bkd * L_);
#pragma unroll
        for (int q = 0; q < 4; ++q)
            ov[t * 4 + q] = make_float4(yv[q * 4], yv[q * 4 + 1],
                                        yv[q * 4 + 2], yv[q * 4 + 3]);
    }
}

extern "C" void kernel_launch(void* const* d_in, const int* in_sizes, int n_in,
                              void* d_out, int out_size, void* d_ws, size_t ws_size,
                              hipStream_t stream) {
    const float* xs = (const float*)d_in[0];       // (B,K,D,L)
    const float* A_logs = (const float*)d_in[1];   // (K*D, N)
    const float* Ds = (const float*)d_in[2];       // (K*D,)
    const float* dtw = (const float*)d_in[3];      // (K,D,R)
    const float* dtb = (const float*)d_in[4];      // (K,D)
    const float* xpw = (const float*)d_in[5];      // (K,C,D)
    float* out = (float*)d_out;                    // (B,K,D,L) fp32

    uint4* BCc = (uint4*)d_ws;                     // 16*16*4*128 uint4 = 2 MB
    float* dts_ws = (float*)(BCc + (size_t)B_ * K_ * 16 * 4 * TPR);  // 768 KB

    proj_kernel<<<dim3(B_ * K_, 32, 2), 256, 0, stream>>>(xs, xpw, BCc, dts_ws);
    scan_kernel<<<B_ * K_ * D_, 256, 0, stream>>>(
        xs, A_logs, Ds, dtw, dtb, dts_ws, BCc, out);
}